// Round 10
// baseline (926.539 us; speedup 1.0000x reference)
//
#include <hip/hip_runtime.h>
#include <hip/hip_fp16.h>
#include <stdint.h>
#include <math.h>

#define HID 64
#define DIN 128
#define DOUT 40
#define N_LAYERS 8
#define DEGCAP 64   // padded adjacency stride; P(deg>64 | Poisson(16)) ~ 1e-15

typedef _Float16 half8 __attribute__((ext_vector_type(8)));
typedef float f32x4 __attribute__((ext_vector_type(4)));

static inline int cdiv(int a, int b) { return (a + b - 1) / b; }

// ---------- edge-index layout detection (int32 vs int64 storage) ----------
__global__ void detect_i64(const uint32_t* __restrict__ ei, int* __restrict__ flag) {
    int t = threadIdx.x;
    uint32_t w = ei[2 * t + 1];
    unsigned long long nz = __ballot(w != 0u);
    if (t == 0) *flag = (nz == 0ull) ? 1 : 0;
}

__device__ __forceinline__ int edge_src(const uint32_t* ei, int is64, int E, int e) {
    return is64 ? (int)ei[2 * e] : (int)ei[e];
}
__device__ __forceinline__ int edge_dst(const uint32_t* ei, int is64, int E, int e) {
    return is64 ? (int)ei[2 * (size_t)E + 2 * e] : (int)ei[(size_t)E + e];
}

// ---------- padded-CSR build: single edge pass, no scans, no tickets ----------
__global__ void init_cnt(int* __restrict__ cnt, int n) {
    int v = blockIdx.x * blockDim.x + threadIdx.x;
    if (v < n) cnt[v] = 0;
}

__global__ void build_csr(const uint32_t* __restrict__ ei, const int* __restrict__ flag,
                          int* __restrict__ cnt, int* __restrict__ padded, int E) {
    int e = blockIdx.x * blockDim.x + threadIdx.x;
    if (e >= E) return;
    int is64 = *flag;
    int s = edge_src(ei, is64, E, e);
    int d = edge_dst(ei, is64, E, e);
    int pos = atomicAdd(&cnt[d], 1);
    if (pos < DEGCAP)
        __builtin_nontemporal_store(s, &padded[(size_t)d * DEGCAP + pos]);
}

__global__ void compute_dinv(const int* __restrict__ cnt, float* __restrict__ dinv, int n) {
    int v = blockIdx.x * blockDim.x + threadIdx.x;
    if (v < n) dinv[v] = rsqrtf((float)(cnt[v] + 1));
}

// ---------- Bp_i = fp16(beta_i * W_i + (1-beta_i) * I), stored transposed [n][k] ----
__global__ void make_bp(const float* __restrict__ convw, __half* __restrict__ Bp) {
    int i = blockIdx.x;
    float beta = logf(0.5f / (float)(i + 1) + 1.f);
    const float* W = convw + (size_t)i * HID * HID;
    __half* out = Bp + (size_t)i * HID * HID;
    for (int idx = threadIdx.x; idx < HID * HID; idx += blockDim.x) {
        int k = idx >> 6, nn = idx & 63;
        float v = beta * W[k * HID + nn] + ((k == nn) ? (1.f - beta) : 0.f);
        out[nn * HID + k] = __float2half(v);
    }
}

// ---------- W1h = fp16(W1^T) : [64 n][128 k] ----------
__global__ void make_w1t(const float* __restrict__ W1, __half* __restrict__ W1h) {
    for (int idx = threadIdx.x; idx < DIN * HID; idx += blockDim.x) {
        int nn = idx >> 7, k = idx & 127;
        W1h[nn * DIN + k] = __float2half(W1[k * HID + nn]);
    }
}

// ---------- MFMA input layer: h0h = fp16(relu(x@W1+b1)); hp = fp16(dinv*h0) ----------
__global__ void __launch_bounds__(256) mlp_in_mfma(
        const float* __restrict__ x, const __half* __restrict__ W1h,
        const float* __restrict__ b1, const float* __restrict__ dinv,
        __half2* __restrict__ hp2, __half2* __restrict__ h0h2, int n) {
    __shared__ __align__(16) ushort Bs[64 * 136];    // [n][k] pad +8
    __shared__ __align__(16) ushort As[128 * 136];   // [node][k] pad +8; reused for out
    int t = threadIdx.x;
    {
        const __half2* W2 = (const __half2*)W1h;
        for (int i = t; i < 64 * 64; i += 256) {
            int bn = i >> 6, kp = i & 63;
            *(__half2*)&Bs[bn * 136 + 2 * kp] = W2[bn * 64 + kp];
        }
    }
    int node0 = blockIdx.x * 128;
    {
        const float4* x4 = (const float4*)x;
        for (int i = t; i < 128 * 32; i += 256) {
            int nd = i >> 5, q = i & 31;
            int node = node0 + nd;
            float4 xv = (node < n) ? x4[(size_t)node * 32 + q]
                                   : make_float4(0.f, 0.f, 0.f, 0.f);
            *(__half2*)&As[nd * 136 + q * 4]     = __floats2half2_rn(xv.x, xv.y);
            *(__half2*)&As[nd * 136 + q * 4 + 2] = __floats2half2_rn(xv.z, xv.w);
        }
    }
    __syncthreads();
    int lane = t & 63, wv = t >> 6;
    int nl = lane & 15, quad = lane >> 4;
    int m_base = wv * 32;
    f32x4 C[2][4];
#pragma unroll
    for (int mt = 0; mt < 2; mt++)
#pragma unroll
        for (int nt = 0; nt < 4; nt++) C[mt][nt] = (f32x4)0.f;
#pragma unroll
    for (int kc = 0; kc < 4; kc++) {
        half8 a[2], b[4];
#pragma unroll
        for (int mt = 0; mt < 2; mt++)
            a[mt] = *(const half8*)&As[(m_base + mt * 16 + nl) * 136 + kc * 32 + quad * 8];
#pragma unroll
        for (int nt = 0; nt < 4; nt++)
            b[nt] = *(const half8*)&Bs[(nt * 16 + nl) * 136 + kc * 32 + quad * 8];
#pragma unroll
        for (int mt = 0; mt < 2; mt++)
#pragma unroll
            for (int nt = 0; nt < 4; nt++)
                C[mt][nt] = __builtin_amdgcn_mfma_f32_16x16x32_f16(a[mt], b[nt],
                                                                   C[mt][nt], 0, 0, 0);
    }
    __syncthreads();
#pragma unroll
    for (int nt = 0; nt < 4; nt++) {
        float bias = b1[nt * 16 + nl];
#pragma unroll
        for (int mt = 0; mt < 2; mt++) {
#pragma unroll
            for (int reg = 0; reg < 4; reg++) {
                int nd = m_base + mt * 16 + quad * 4 + reg;
                float v = fmaxf(C[mt][nt][reg] + bias, 0.f);
                As[nd * 72 + nt * 16 + nl] = __half_as_ushort(__float2half(v));
            }
        }
    }
    __syncthreads();
    for (int i = t; i < 128 * 32; i += 256) {
        int nd = i >> 5, kp = i & 31;
        int node = node0 + nd;
        if (node < n) {
            __half2 h = *(const __half2*)&As[nd * 72 + 2 * kp];
            h0h2[(size_t)node * 32 + kp] = h;
            float dv = dinv[node];
            float2 f = __half22float2(h);
            hp2[(size_t)node * 32 + kp] = __floats2half2_rn(f.x * dv, f.y * dv);
        }
    }
}

// ---------- SpMM half2 on padded rows: agg' = 0.9*dv*(self + sum hp[src]) ----------
__global__ void spmm_h2(const __half2* __restrict__ hp2, const int* __restrict__ cnt,
                        const int* __restrict__ padded, const float* __restrict__ dinv,
                        __half2* __restrict__ agg, int n) {
    int v = (blockIdx.x * blockDim.x + threadIdx.x) >> 6;
    int lane = threadIdx.x & 63;
    if (v >= n) return;
    int f2 = lane & 31, g = lane >> 5;
    const int* row = padded + (size_t)v * DEGCAP;
    int c = min(cnt[v], DEGCAP);
    int h1 = (c + 1) >> 1;
    int e = g ? h1 : 0;
    int end = g ? c : h1;
    float ax = 0.f, ay = 0.f;
    if (g == 0) {
        float2 s = __half22float2(hp2[(size_t)v * 32 + f2]);
        ax = s.x; ay = s.y;
    }
    for (; e + 8 <= end; e += 8) {
        int s0 = __builtin_nontemporal_load(&row[e]);
        int s1 = __builtin_nontemporal_load(&row[e + 1]);
        int s2 = __builtin_nontemporal_load(&row[e + 2]);
        int s3 = __builtin_nontemporal_load(&row[e + 3]);
        int s4 = __builtin_nontemporal_load(&row[e + 4]);
        int s5 = __builtin_nontemporal_load(&row[e + 5]);
        int s6 = __builtin_nontemporal_load(&row[e + 6]);
        int s7 = __builtin_nontemporal_load(&row[e + 7]);
        float2 f0 = __half22float2(hp2[(size_t)s0 * 32 + f2]);
        float2 f1 = __half22float2(hp2[(size_t)s1 * 32 + f2]);
        float2 f2v = __half22float2(hp2[(size_t)s2 * 32 + f2]);
        float2 f3 = __half22float2(hp2[(size_t)s3 * 32 + f2]);
        float2 f4 = __half22float2(hp2[(size_t)s4 * 32 + f2]);
        float2 f5 = __half22float2(hp2[(size_t)s5 * 32 + f2]);
        float2 f6 = __half22float2(hp2[(size_t)s6 * 32 + f2]);
        float2 f7 = __half22float2(hp2[(size_t)s7 * 32 + f2]);
        ax += ((f0.x + f1.x) + (f2v.x + f3.x)) + ((f4.x + f5.x) + (f6.x + f7.x));
        ay += ((f0.y + f1.y) + (f2v.y + f3.y)) + ((f4.y + f5.y) + (f6.y + f7.y));
    }
    if (e + 4 <= end) {
        int s0 = __builtin_nontemporal_load(&row[e]);
        int s1 = __builtin_nontemporal_load(&row[e + 1]);
        int s2 = __builtin_nontemporal_load(&row[e + 2]);
        int s3 = __builtin_nontemporal_load(&row[e + 3]);
        float2 f0 = __half22float2(hp2[(size_t)s0 * 32 + f2]);
        float2 f1 = __half22float2(hp2[(size_t)s1 * 32 + f2]);
        float2 f2v = __half22float2(hp2[(size_t)s2 * 32 + f2]);
        float2 f3 = __half22float2(hp2[(size_t)s3 * 32 + f2]);
        ax += (f0.x + f1.x) + (f2v.x + f3.x);
        ay += (f0.y + f1.y) + (f2v.y + f3.y);
        e += 4;
    }
    for (; e < end; ++e) {
        float2 fv = __half22float2(hp2[(size_t)__builtin_nontemporal_load(&row[e]) * 32 + f2]);
        ax += fv.x; ay += fv.y;
    }
    ax += __shfl_xor(ax, 32);
    ay += __shfl_xor(ay, 32);
    if (g == 0) {
        float s = 0.9f * dinv[v];
        __half2 hv = __floats2half2_rn(s * ax, s * ay);
        uint32_t bits;
        __builtin_memcpy(&bits, &hv, 4);
        __builtin_nontemporal_store(bits, (uint32_t*)&agg[(size_t)v * 32 + f2]);
    }
}

// ---------- MFMA dense layer: hpn = fp16((dinv?)*relu((agg + 0.1*h0) @ Bp)) ----------
__global__ void __launch_bounds__(256) layer_mfma(
        const __half2* __restrict__ agg, const __half2* __restrict__ h0h,
        const __half* __restrict__ Bp, const float* __restrict__ dinv,
        int scale_out, __half2* __restrict__ hpn, int n) {
    __shared__ __align__(16) ushort Bs[64 * 72];
    __shared__ __align__(16) ushort As[128 * 72];
    int t = threadIdx.x;
    {
        const __half2* B2 = (const __half2*)Bp;
        for (int i = t; i < 64 * 32; i += 256) {
            int bn = i >> 5, kp = i & 31;
            *(__half2*)&Bs[bn * 72 + 2 * kp] = B2[bn * 32 + kp];
        }
    }
    int node0 = blockIdx.x * 128;
    for (int i = t; i < 128 * 32; i += 256) {
        int nd = i >> 5, kp = i & 31;
        int node = node0 + nd;
        __half2 o;
        if (node < n) {
            float2 a = __half22float2(agg[(size_t)node * 32 + kp]);
            float2 h = __half22float2(h0h[(size_t)node * 32 + kp]);
            o = __floats2half2_rn(a.x + 0.1f * h.x, a.y + 0.1f * h.y);
        } else {
            o = __floats2half2_rn(0.f, 0.f);
        }
        *(__half2*)&As[nd * 72 + 2 * kp] = o;
    }
    __syncthreads();
    int lane = t & 63, wv = t >> 6;
    int nl = lane & 15, quad = lane >> 4;
    int m_base = wv * 32;
    f32x4 C[2][4];
#pragma unroll
    for (int mt = 0; mt < 2; mt++)
#pragma unroll
        for (int nt = 0; nt < 4; nt++) C[mt][nt] = (f32x4)0.f;
#pragma unroll
    for (int kc = 0; kc < 2; kc++) {
        half8 a[2], b[4];
#pragma unroll
        for (int mt = 0; mt < 2; mt++)
            a[mt] = *(const half8*)&As[(m_base + mt * 16 + nl) * 72 + kc * 32 + quad * 8];
#pragma unroll
        for (int nt = 0; nt < 4; nt++)
            b[nt] = *(const half8*)&Bs[(nt * 16 + nl) * 72 + kc * 32 + quad * 8];
#pragma unroll
        for (int mt = 0; mt < 2; mt++)
#pragma unroll
            for (int nt = 0; nt < 4; nt++)
                C[mt][nt] = __builtin_amdgcn_mfma_f32_16x16x32_f16(a[mt], b[nt],
                                                                   C[mt][nt], 0, 0, 0);
    }
    __syncthreads();
#pragma unroll
    for (int mt = 0; mt < 2; mt++) {
#pragma unroll
        for (int reg = 0; reg < 4; reg++) {
            int nd = m_base + mt * 16 + quad * 4 + reg;
            int node = node0 + nd;
            float dv = (scale_out && node < n) ? dinv[node] : 1.f;
#pragma unroll
            for (int nt = 0; nt < 4; nt++) {
                float v = fmaxf(C[mt][nt][reg], 0.f) * dv;
                As[nd * 72 + nt * 16 + nl] = __half_as_ushort(__float2half(v));
            }
        }
    }
    __syncthreads();
    for (int i = t; i < 128 * 32; i += 256) {
        int nd = i >> 5, kp = i & 31;
        int node = node0 + nd;
        if (node < n) hpn[(size_t)node * 32 + kp] = *(const __half2*)&As[nd * 72 + 2 * kp];
    }
}

// ---------- y = h @ W2 + b2  (h fp16) ----------
__global__ void mlp_out(const __half* __restrict__ h, const float* __restrict__ W2,
                        const float* __restrict__ b2, float* __restrict__ y, int n) {
    __shared__ float hs[32 * HID];
    __shared__ float W2s[HID * DOUT];
    __shared__ float b2s[DOUT];
    int t = threadIdx.x;
    for (int i = t; i < HID * DOUT; i += 256) W2s[i] = W2[i];
    if (t < DOUT) b2s[t] = b2[t];
    int node0 = blockIdx.x * 32;
    for (int i = t; i < 32 * HID; i += 256) {
        int node = node0 + (i >> 6);
        hs[i] = (node < n) ? __half2float(h[(size_t)node0 * HID + i]) : 0.f;
    }
    __syncthreads();
    for (int idx = t; idx < 32 * DOUT; idx += 256) {
        int nloc = idx / DOUT, fo = idx % DOUT;
        int node = node0 + nloc;
        if (node >= n) continue;
        float dot = b2s[fo];
#pragma unroll 8
        for (int k = 0; k < HID; k++) dot += hs[nloc * HID + k] * W2s[k * DOUT + fo];
        y[(size_t)node * DOUT + fo] = dot;
    }
}

extern "C" void kernel_launch(void* const* d_in, const int* in_sizes, int n_in,
                              void* d_out, int out_size, void* d_ws, size_t ws_size,
                              hipStream_t stream) {
    const float*    x     = (const float*)d_in[0];
    const uint32_t* ei    = (const uint32_t*)d_in[1];
    const float*    W1    = (const float*)d_in[2];
    const float*    b1    = (const float*)d_in[3];
    const float*    convw = (const float*)d_in[4];
    const float*    W2    = (const float*)d_in[5];
    const float*    b2    = (const float*)d_in[6];
    float*          y     = (float*)d_out;

    int N = in_sizes[0] / DIN;
    int E = in_sizes[1] / 2;

    char* ws = (char*)d_ws;
    size_t off = 0;
    auto alloc = [&](size_t bytes) -> char* {
        char* p = ws + off;
        off = (off + bytes + 255) & ~(size_t)255;
        return p;
    };
    int*     flag      = (int*)alloc(4);
    int*     cnt       = (int*)alloc((size_t)N * 4);
    float*   dinv      = (float*)alloc((size_t)N * 4);
    int*     padded    = (int*)alloc((size_t)N * DEGCAP * 4);
    __half*  Bp        = (__half*)alloc((size_t)N_LAYERS * HID * HID * 2);
    __half*  W1h       = (__half*)alloc((size_t)DIN * HID * 2);
    __half*  h0h       = (__half*)alloc((size_t)N * HID * 2);
    __half2* aggb      = (__half2*)alloc((size_t)N * HID * 2);
    __half*  hpA       = (__half*)alloc((size_t)N * HID * 2);
    __half*  hpB       = (__half*)alloc((size_t)N * HID * 2);

    detect_i64<<<1, 64, 0, stream>>>(ei, flag);
    make_bp<<<N_LAYERS, 256, 0, stream>>>(convw, Bp);
    make_w1t<<<1, 256, 0, stream>>>(W1, W1h);
    init_cnt<<<cdiv(N, 256), 256, 0, stream>>>(cnt, N);
    build_csr<<<cdiv(E, 256), 256, 0, stream>>>(ei, flag, cnt, padded, E);
    compute_dinv<<<cdiv(N, 256), 256, 0, stream>>>(cnt, dinv, N);

    mlp_in_mfma<<<cdiv(N, 128), 256, 0, stream>>>(x, W1h, b1, dinv,
                                                  (__half2*)hpA, (__half2*)h0h, N);

    __half* cur = hpA;
    __half* nxt = hpB;
    for (int i = 0; i < N_LAYERS; i++) {
        int scale_out = (i < N_LAYERS - 1) ? 1 : 0;
        spmm_h2<<<cdiv(N, 4), 256, 0, stream>>>((const __half2*)cur, cnt, padded,
                                                dinv, aggb, N);
        layer_mfma<<<cdiv(N, 128), 256, 0, stream>>>(aggb, (const __half2*)h0h,
                                                     Bp + (size_t)i * HID * HID,
                                                     dinv, scale_out, (__half2*)nxt, N);
        __half* tmp = cur; cur = nxt; nxt = tmp;
    }
    mlp_out<<<cdiv(N, 32), 256, 0, stream>>>(cur, W2, b2, y, N);
}

// Round 11
// 745.602 us; speedup vs baseline: 1.2427x; 1.2427x over previous
//
#include <hip/hip_runtime.h>
#include <hip/hip_fp16.h>
#include <stdint.h>
#include <math.h>

#define HID 64
#define DIN 128
#define DOUT 40
#define N_LAYERS 8

typedef _Float16 half8 __attribute__((ext_vector_type(8)));
typedef float f32x4 __attribute__((ext_vector_type(4)));

static inline int cdiv(int a, int b) { return (a + b - 1) / b; }

// ---------- edge-index layout detection (int32 vs int64 storage) ----------
__global__ void detect_i64(const uint32_t* __restrict__ ei, int* __restrict__ flag) {
    int t = threadIdx.x;
    uint32_t w = ei[2 * t + 1];
    unsigned long long nz = __ballot(w != 0u);
    if (t == 0) *flag = (nz == 0ull) ? 1 : 0;
}

__device__ __forceinline__ int edge_src(const uint32_t* ei, int is64, int E, int e) {
    return is64 ? (int)ei[2 * e] : (int)ei[e];
}
__device__ __forceinline__ int edge_dst(const uint32_t* ei, int is64, int E, int e) {
    return is64 ? (int)ei[2 * (size_t)E + 2 * e] : (int)ei[(size_t)E + e];
}

// ---------- CSR construction (split-phase ticket; proven R8 path) ----------
__global__ void init_cnt(int* __restrict__ cnt, int n) {
    int v = blockIdx.x * blockDim.x + threadIdx.x;
    if (v < n) cnt[v] = 0;
}

__global__ void count_pos(const uint32_t* __restrict__ ei, const int* __restrict__ flag,
                          int* __restrict__ cnt, int* __restrict__ pw, int E) {
    int e = blockIdx.x * blockDim.x + threadIdx.x;
    if (e >= E) return;
    int is64 = *flag;
    int d = edge_dst(ei, is64, E, e);
    pw[e] = atomicAdd(&cnt[d], 1);
}

__global__ void scan1(const int* __restrict__ cnt, int* __restrict__ row_start,
                      int* __restrict__ blocksum, int n) {
    __shared__ int sh[256];
    int t = threadIdx.x;
    int v = blockIdx.x * 256 + t;
    int val = (v < n) ? cnt[v] : 0;
    sh[t] = val;
    __syncthreads();
    for (int o = 1; o < 256; o <<= 1) {
        int y = (t >= o) ? sh[t - o] : 0;
        __syncthreads();
        sh[t] += y;
        __syncthreads();
    }
    if (v < n) row_start[v] = sh[t] - val;
    if (t == 255) blocksum[blockIdx.x] = sh[255];
}

__global__ void scan2(int* __restrict__ blocksum, int nb) {
    __shared__ int sh[512];
    int t = threadIdx.x;
    int val = (t < nb) ? blocksum[t] : 0;
    sh[t] = val;
    __syncthreads();
    for (int o = 1; o < 512; o <<= 1) {
        int y = (t >= o) ? sh[t - o] : 0;
        __syncthreads();
        sh[t] += y;
        __syncthreads();
    }
    if (t < nb) blocksum[t] = sh[t] - val;
}

__global__ void scan3(int* __restrict__ row_start, const int* __restrict__ blocksum, int n) {
    int v = blockIdx.x * 256 + threadIdx.x;
    if (v < n) row_start[v] += blocksum[v >> 8];
}

__global__ void compute_dinv(const int* __restrict__ cnt, float* __restrict__ dinv, int n) {
    int v = blockIdx.x * blockDim.x + threadIdx.x;
    if (v < n) dinv[v] = rsqrtf((float)(cnt[v] + 1));
}

__global__ void scatter_pos(const uint32_t* __restrict__ ei, const int* __restrict__ flag,
                            const int* __restrict__ row_start, const int* __restrict__ pw,
                            int* __restrict__ csr_src, int E) {
    int e = blockIdx.x * blockDim.x + threadIdx.x;
    if (e >= E) return;
    int is64 = *flag;
    int s = edge_src(ei, is64, E, e);
    int d = edge_dst(ei, is64, E, e);
    csr_src[row_start[d] + pw[e]] = s;
}

// ---------- Bp_i = fp16(beta_i * W_i + (1-beta_i) * I), stored transposed [n][k] ----
__global__ void make_bp(const float* __restrict__ convw, __half* __restrict__ Bp) {
    int i = blockIdx.x;
    float beta = logf(0.5f / (float)(i + 1) + 1.f);
    const float* W = convw + (size_t)i * HID * HID;
    __half* out = Bp + (size_t)i * HID * HID;
    for (int idx = threadIdx.x; idx < HID * HID; idx += blockDim.x) {
        int k = idx >> 6, nn = idx & 63;
        float v = beta * W[k * HID + nn] + ((k == nn) ? (1.f - beta) : 0.f);
        out[nn * HID + k] = __float2half(v);
    }
}

// ---------- W1h = fp16(W1^T) : [64 n][128 k] ----------
__global__ void make_w1t(const float* __restrict__ W1, __half* __restrict__ W1h) {
    for (int idx = threadIdx.x; idx < DIN * HID; idx += blockDim.x) {
        int nn = idx >> 7, k = idx & 127;
        W1h[nn * DIN + k] = __float2half(W1[k * HID + nn]);
    }
}

// ---------- MFMA input layer: h0h = fp16(relu(x@W1+b1)); hp = fp16(dinv*h0) ----------
__global__ void __launch_bounds__(256) mlp_in_mfma(
        const float* __restrict__ x, const __half* __restrict__ W1h,
        const float* __restrict__ b1, const float* __restrict__ dinv,
        __half2* __restrict__ hp2, __half2* __restrict__ h0h2, int n) {
    __shared__ __align__(16) ushort Bs[64 * 136];
    __shared__ __align__(16) ushort As[128 * 136];
    int t = threadIdx.x;
    {
        const __half2* W2 = (const __half2*)W1h;
        for (int i = t; i < 64 * 64; i += 256) {
            int bn = i >> 6, kp = i & 63;
            *(__half2*)&Bs[bn * 136 + 2 * kp] = W2[bn * 64 + kp];
        }
    }
    int node0 = blockIdx.x * 128;
    {
        const float4* x4 = (const float4*)x;
        for (int i = t; i < 128 * 32; i += 256) {
            int nd = i >> 5, q = i & 31;
            int node = node0 + nd;
            float4 xv = (node < n) ? x4[(size_t)node * 32 + q]
                                   : make_float4(0.f, 0.f, 0.f, 0.f);
            *(__half2*)&As[nd * 136 + q * 4]     = __floats2half2_rn(xv.x, xv.y);
            *(__half2*)&As[nd * 136 + q * 4 + 2] = __floats2half2_rn(xv.z, xv.w);
        }
    }
    __syncthreads();
    int lane = t & 63, wv = t >> 6;
    int nl = lane & 15, quad = lane >> 4;
    int m_base = wv * 32;
    f32x4 C[2][4];
#pragma unroll
    for (int mt = 0; mt < 2; mt++)
#pragma unroll
        for (int nt = 0; nt < 4; nt++) C[mt][nt] = (f32x4)0.f;
#pragma unroll
    for (int kc = 0; kc < 4; kc++) {
        half8 a[2], b[4];
#pragma unroll
        for (int mt = 0; mt < 2; mt++)
            a[mt] = *(const half8*)&As[(m_base + mt * 16 + nl) * 136 + kc * 32 + quad * 8];
#pragma unroll
        for (int nt = 0; nt < 4; nt++)
            b[nt] = *(const half8*)&Bs[(nt * 16 + nl) * 136 + kc * 32 + quad * 8];
#pragma unroll
        for (int mt = 0; mt < 2; mt++)
#pragma unroll
            for (int nt = 0; nt < 4; nt++)
                C[mt][nt] = __builtin_amdgcn_mfma_f32_16x16x32_f16(a[mt], b[nt],
                                                                   C[mt][nt], 0, 0, 0);
    }
    __syncthreads();
#pragma unroll
    for (int nt = 0; nt < 4; nt++) {
        float bias = b1[nt * 16 + nl];
#pragma unroll
        for (int mt = 0; mt < 2; mt++) {
#pragma unroll
            for (int reg = 0; reg < 4; reg++) {
                int nd = m_base + mt * 16 + quad * 4 + reg;
                float v = fmaxf(C[mt][nt][reg] + bias, 0.f);
                As[nd * 72 + nt * 16 + nl] = __half_as_ushort(__float2half(v));
            }
        }
    }
    __syncthreads();
    for (int i = t; i < 128 * 32; i += 256) {
        int nd = i >> 5, kp = i & 31;
        int node = node0 + nd;
        if (node < n) {
            __half2 h = *(const __half2*)&As[nd * 72 + 2 * kp];
            h0h2[(size_t)node * 32 + kp] = h;
            float dv = dinv[node];
            float2 f = __half22float2(h);
            hp2[(size_t)node * 32 + kp] = __floats2half2_rn(f.x * dv, f.y * dv);
        }
    }
}

// ---------- fused layer: gather(spmm) -> blend -> MFMA dense -> relu -> store ------
// 512 threads = 8 waves; 128-node tile; wave w gathers nodes [w*16, w*16+16) and
// computes the M=16 MFMA strip for the same rows.
__global__ void __launch_bounds__(512) gcnii_fused(
        const __half2* __restrict__ hp2, const __half2* __restrict__ h0h2,
        const int* __restrict__ row_start, const int* __restrict__ cnt,
        const int* __restrict__ csr_src, const float* __restrict__ dinv,
        const __half* __restrict__ Bp, int scale_out,
        __half2* __restrict__ hpn, int n) {
    __shared__ __align__(16) ushort Bs[64 * 72];    // B' [n][k], pad +8
    __shared__ __align__(16) ushort As[128 * 72];   // out rows [node][k]; reused for result
    int t = threadIdx.x;
    // stage B'
    {
        const __half2* B2 = (const __half2*)Bp;
        for (int i = t; i < 64 * 32; i += 512) {
            int bn = i >> 5, kp = i & 31;
            *(__half2*)&Bs[bn * 72 + 2 * kp] = B2[bn * 32 + kp];
        }
    }
    int node0 = blockIdx.x * 128;
    int lane = t & 63, w = t >> 6;
    int f2 = lane & 31, g = lane >> 5;
    // phase 1: gather 16 nodes per wave, write blended fp16 row into As
    for (int i = 0; i < 16; i++) {
        int nd = w * 16 + i;
        int v = node0 + nd;
        float ax = 0.f, ay = 0.f;
        if (v < n) {
            int j = row_start[v];
            int c = cnt[v];
            int h1 = (c + 1) >> 1;
            int e = j + (g ? h1 : 0);
            int end = g ? (j + c) : (j + h1);
            if (g == 0) {
                float2 s = __half22float2(hp2[(size_t)v * 32 + f2]);
                ax = s.x; ay = s.y;
            }
            for (; e + 8 <= end; e += 8) {
                int s0 = csr_src[e],     s1 = csr_src[e + 1];
                int s2 = csr_src[e + 2], s3 = csr_src[e + 3];
                int s4 = csr_src[e + 4], s5 = csr_src[e + 5];
                int s6 = csr_src[e + 6], s7 = csr_src[e + 7];
                float2 f0 = __half22float2(hp2[(size_t)s0 * 32 + f2]);
                float2 f1 = __half22float2(hp2[(size_t)s1 * 32 + f2]);
                float2 f2v = __half22float2(hp2[(size_t)s2 * 32 + f2]);
                float2 f3 = __half22float2(hp2[(size_t)s3 * 32 + f2]);
                float2 f4 = __half22float2(hp2[(size_t)s4 * 32 + f2]);
                float2 f5 = __half22float2(hp2[(size_t)s5 * 32 + f2]);
                float2 f6 = __half22float2(hp2[(size_t)s6 * 32 + f2]);
                float2 f7 = __half22float2(hp2[(size_t)s7 * 32 + f2]);
                ax += ((f0.x + f1.x) + (f2v.x + f3.x)) + ((f4.x + f5.x) + (f6.x + f7.x));
                ay += ((f0.y + f1.y) + (f2v.y + f3.y)) + ((f4.y + f5.y) + (f6.y + f7.y));
            }
            if (e + 4 <= end) {
                int s0 = csr_src[e],     s1 = csr_src[e + 1];
                int s2 = csr_src[e + 2], s3 = csr_src[e + 3];
                float2 f0 = __half22float2(hp2[(size_t)s0 * 32 + f2]);
                float2 f1 = __half22float2(hp2[(size_t)s1 * 32 + f2]);
                float2 f2v = __half22float2(hp2[(size_t)s2 * 32 + f2]);
                float2 f3 = __half22float2(hp2[(size_t)s3 * 32 + f2]);
                ax += (f0.x + f1.x) + (f2v.x + f3.x);
                ay += (f0.y + f1.y) + (f2v.y + f3.y);
                e += 4;
            }
            for (; e < end; ++e) {
                float2 fv = __half22float2(hp2[(size_t)csr_src[e] * 32 + f2]);
                ax += fv.x; ay += fv.y;
            }
        }
        ax += __shfl_xor(ax, 32);
        ay += __shfl_xor(ay, 32);
        if (g == 0) {
            __half2 o = __floats2half2_rn(0.f, 0.f);
            if (v < n) {
                float s = 0.9f * dinv[v];
                float2 h = __half22float2(h0h2[(size_t)v * 32 + f2]);
                o = __floats2half2_rn(s * ax + 0.1f * h.x, s * ay + 0.1f * h.y);
            }
            *(__half2*)&As[nd * 72 + 2 * f2] = o;
        }
    }
    __syncthreads();
    // phase 2: MFMA — wave w computes rows [w*16, w*16+16)
    int nl = lane & 15, quad = lane >> 4;
    int m_base = w * 16;
    f32x4 C[4];
#pragma unroll
    for (int nt = 0; nt < 4; nt++) C[nt] = (f32x4)0.f;
#pragma unroll
    for (int kc = 0; kc < 2; kc++) {
        half8 a = *(const half8*)&As[(m_base + nl) * 72 + kc * 32 + quad * 8];
        half8 b[4];
#pragma unroll
        for (int nt = 0; nt < 4; nt++)
            b[nt] = *(const half8*)&Bs[(nt * 16 + nl) * 72 + kc * 32 + quad * 8];
#pragma unroll
        for (int nt = 0; nt < 4; nt++)
            C[nt] = __builtin_amdgcn_mfma_f32_16x16x32_f16(a, b[nt], C[nt], 0, 0, 0);
    }
    // epilogue: wave w only touches its own rows -> no barrier needed before write
#pragma unroll
    for (int reg = 0; reg < 4; reg++) {
        int nd = m_base + quad * 4 + reg;
        int node = node0 + nd;
        float dv = (scale_out && node < n) ? dinv[node] : 1.f;
#pragma unroll
        for (int nt = 0; nt < 4; nt++) {
            float v = fmaxf(C[nt][reg], 0.f) * dv;
            As[nd * 72 + nt * 16 + nl] = __half_as_ushort(__float2half(v));
        }
    }
    __syncthreads();
    // coalesced store
    for (int i = t; i < 128 * 32; i += 512) {
        int nd = i >> 5, kp = i & 31;
        int node = node0 + nd;
        if (node < n) hpn[(size_t)node * 32 + kp] = *(const __half2*)&As[nd * 72 + 2 * kp];
    }
}

// ---------- y = h @ W2 + b2  (h fp16) ----------
__global__ void mlp_out(const __half* __restrict__ h, const float* __restrict__ W2,
                        const float* __restrict__ b2, float* __restrict__ y, int n) {
    __shared__ float hs[32 * HID];
    __shared__ float W2s[HID * DOUT];
    __shared__ float b2s[DOUT];
    int t = threadIdx.x;
    for (int i = t; i < HID * DOUT; i += 256) W2s[i] = W2[i];
    if (t < DOUT) b2s[t] = b2[t];
    int node0 = blockIdx.x * 32;
    for (int i = t; i < 32 * HID; i += 256) {
        int node = node0 + (i >> 6);
        hs[i] = (node < n) ? __half2float(h[(size_t)node0 * HID + i]) : 0.f;
    }
    __syncthreads();
    for (int idx = t; idx < 32 * DOUT; idx += 256) {
        int nloc = idx / DOUT, fo = idx % DOUT;
        int node = node0 + nloc;
        if (node >= n) continue;
        float dot = b2s[fo];
#pragma unroll 8
        for (int k = 0; k < HID; k++) dot += hs[nloc * HID + k] * W2s[k * DOUT + fo];
        y[(size_t)node * DOUT + fo] = dot;
    }
}

extern "C" void kernel_launch(void* const* d_in, const int* in_sizes, int n_in,
                              void* d_out, int out_size, void* d_ws, size_t ws_size,
                              hipStream_t stream) {
    const float*    x     = (const float*)d_in[0];
    const uint32_t* ei    = (const uint32_t*)d_in[1];
    const float*    W1    = (const float*)d_in[2];
    const float*    b1    = (const float*)d_in[3];
    const float*    convw = (const float*)d_in[4];
    const float*    W2    = (const float*)d_in[5];
    const float*    b2    = (const float*)d_in[6];
    float*          y     = (float*)d_out;

    int N = in_sizes[0] / DIN;
    int E = in_sizes[1] / 2;

    char* ws = (char*)d_ws;
    size_t off = 0;
    auto alloc = [&](size_t bytes) -> char* {
        char* p = ws + off;
        off = (off + bytes + 255) & ~(size_t)255;
        return p;
    };
    int*     flag      = (int*)alloc(4);
    int*     cnt       = (int*)alloc((size_t)N * 4);
    int*     row_start = (int*)alloc((size_t)N * 4);
    float*   dinv      = (float*)alloc((size_t)N * 4);
    int*     blocksum  = (int*)alloc(512 * 4);
    int*     pw        = (int*)alloc((size_t)E * 4);
    int*     csr_src   = (int*)alloc((size_t)E * 4);
    __half*  Bp        = (__half*)alloc((size_t)N_LAYERS * HID * HID * 2);
    __half*  W1h       = (__half*)alloc((size_t)DIN * HID * 2);
    __half*  h0h       = (__half*)alloc((size_t)N * HID * 2);
    __half*  hpA       = (__half*)alloc((size_t)N * HID * 2);
    __half*  hpB       = (__half*)alloc((size_t)N * HID * 2);

    detect_i64<<<1, 64, 0, stream>>>(ei, flag);
    make_bp<<<N_LAYERS, 256, 0, stream>>>(convw, Bp);
    make_w1t<<<1, 256, 0, stream>>>(W1, W1h);
    init_cnt<<<cdiv(N, 256), 256, 0, stream>>>(cnt, N);
    count_pos<<<cdiv(E, 256), 256, 0, stream>>>(ei, flag, cnt, pw, E);
    int nb = cdiv(N, 256);
    scan1<<<nb, 256, 0, stream>>>(cnt, row_start, blocksum, N);
    scan2<<<1, 512, 0, stream>>>(blocksum, nb);
    scan3<<<cdiv(N, 256), 256, 0, stream>>>(row_start, blocksum, N);
    compute_dinv<<<cdiv(N, 256), 256, 0, stream>>>(cnt, dinv, N);
    scatter_pos<<<cdiv(E, 256), 256, 0, stream>>>(ei, flag, row_start, pw, csr_src, E);

    mlp_in_mfma<<<cdiv(N, 128), 256, 0, stream>>>(x, W1h, b1, dinv,
                                                  (__half2*)hpA, (__half2*)h0h, N);

    __half* cur = hpA;
    __half* nxt = hpB;
    for (int i = 0; i < N_LAYERS; i++) {
        int scale_out = (i < N_LAYERS - 1) ? 1 : 0;
        gcnii_fused<<<cdiv(N, 128), 512, 0, stream>>>(
            (const __half2*)cur, (const __half2*)h0h, row_start, cnt, csr_src,
            dinv, Bp + (size_t)i * HID * HID, scale_out, (__half2*)nxt, N);
        __half* tmp = cur; cur = nxt; nxt = tmp;
    }
    mlp_out<<<cdiv(N, 32), 256, 0, stream>>>(cur, W2, b2, y, N);
}